// Round 1
// baseline (454.874 us; speedup 1.0000x reference)
//
#include <hip/hip_runtime.h>

typedef unsigned short u16;
typedef unsigned int   u32;
typedef __attribute__((ext_vector_type(8))) short bf16x8;
typedef __attribute__((ext_vector_type(4))) float f32x4;
typedef __attribute__((ext_vector_type(2))) float f32x2;

#define NFEAT  256
#define NBATCH 8192
#define BT     128   // batch tile per block
#define NBT    (NBATCH / BT)   // 64

__device__ __forceinline__ u16 f2bf(float f) {
    u32 u = __builtin_bit_cast(u32, f);
    return (u16)((u + 0x7FFFu + ((u >> 16) & 1u)) >> 16);
}
__device__ __forceinline__ float bf2f(u16 h) {
    return __builtin_bit_cast(float, (u32)h << 16);
}
__device__ __forceinline__ f32x4 mfma16(bf16x8 a, bf16x8 b, f32x4 c) {
    return __builtin_amdgcn_mfma_f32_16x16x32_bf16(a, b, c, 0, 0, 0);
}

// ---------------------------------------------------------------------------
// prep: w0[f,o] = g_in[f,o] * sign(v_in[f,o,0])   (norm over a length-1 axis)
// ---------------------------------------------------------------------------
__global__ void prep_w0(const float* __restrict__ v_in, const float* __restrict__ g_in,
                        u16* __restrict__ w0) {
    int i = blockIdx.x * blockDim.x + threadIdx.x;   // < 32768
    float v = v_in[i];
    float g = g_in[i];
    w0[i] = f2bf(v >= 0.f ? g : -g);
}

// ---------------------------------------------------------------------------
// prep: weight-normalize v_h0/v_h1/v_out rows -> bf16.  One wave per row.
// rows 0..32767   : w1 (F*128 rows, len 128)
// rows 32768..49151: w2 (F*64 rows, len 128)
// rows 49152..53247: w3 (F*16 rows, len 64)
// ---------------------------------------------------------------------------
__global__ void prep_norm(const float* __restrict__ v_h0, const float* __restrict__ g_h0,
                          const float* __restrict__ v_h1, const float* __restrict__ g_h1,
                          const float* __restrict__ v_out, const float* __restrict__ g_out,
                          u16* __restrict__ w1, u16* __restrict__ w2, u16* __restrict__ w3) {
    const int wave = (blockIdx.x * blockDim.x + threadIdx.x) >> 6;
    const int lane = threadIdx.x & 63;
    if (wave < 32768 + 16384) {
        const float* src; u16* dst; float g;
        if (wave < 32768) {
            src = v_h0 + (size_t)wave * 128; dst = w1 + (size_t)wave * 128; g = g_h0[wave];
        } else {
            int r = wave - 32768;
            src = v_h1 + (size_t)r * 128; dst = w2 + (size_t)r * 128; g = g_h1[r];
        }
        f32x2 v = *(const f32x2*)(src + lane * 2);
        float ss = v.x * v.x + v.y * v.y;
        #pragma unroll
        for (int off = 32; off; off >>= 1) ss += __shfl_xor(ss, off);
        float s = g * rsqrtf(ss);
        u32 pk = (u32)f2bf(v.x * s) | ((u32)f2bf(v.y * s) << 16);
        *(u32*)(dst + lane * 2) = pk;
    } else {
        int r = wave - 49152;   // < 4096
        const float* src = v_out + (size_t)r * 64;
        float v = src[lane];
        float ss = v * v;
        #pragma unroll
        for (int off = 32; off; off >>= 1) ss += __shfl_xor(ss, off);
        float s = g_out[r] * rsqrtf(ss);
        w3[(size_t)r * 64 + lane] = f2bf(v * s);
    }
}

// ---------------------------------------------------------------------------
// prep: x_t[f][b] = bf16( tab[b,0,f] * (1 - tab[b,1,f]) )   (64x64 LDS transpose)
// ---------------------------------------------------------------------------
__global__ void prep_x(const float* __restrict__ tab, u16* __restrict__ x_t) {
    __shared__ u16 tile[64][65];
    const int bb = (blockIdx.x % (NBATCH / 64)) * 64;
    const int ff = (blockIdx.x / (NBATCH / 64)) * 64;
    const int tr = threadIdx.x >> 6;    // 0..3
    const int tc = threadIdx.x & 63;
    #pragma unroll
    for (int i = 0; i < 16; i++) {
        int b = bb + tr + i * 4;
        float val  = tab[(size_t)b * 512 + ff + tc];
        float miss = tab[(size_t)b * 512 + 256 + ff + tc];
        tile[tr + i * 4][tc] = f2bf(val * (1.f - miss));
    }
    __syncthreads();
    #pragma unroll
    for (int i = 0; i < 16; i++) {
        int fr = tr + i * 4;
        x_t[(size_t)(ff + fr) * NBATCH + bb + tc] = tile[tc][fr];
    }
}

// ---------------------------------------------------------------------------
// init logits with bias (re-run every launch: graph-replay safe)
// ---------------------------------------------------------------------------
__global__ void init_logits(float* __restrict__ logits, const float* __restrict__ bias) {
    int i = blockIdx.x * blockDim.x + threadIdx.x;   // < B*16
    logits[i] = bias[i & 15];
}

// ---------------------------------------------------------------------------
// main: per (feature f, batch-tile bt) block, chain 4 layers via MFMA.
// Formulation: D[o][b] = sum_k W[o][k] * H[b][k]  (A=weights, B=activations,
// both read row-major as 16B frags).  D cols give 4 contiguous o per lane ->
// 8B LDS write into next H[b][o].  XOR swizzle (b&7)<<4 on byte addr.
// ---------------------------------------------------------------------------
__global__ __launch_bounds__(256, 2) void nam_main(
    const u16* __restrict__ x_t, const u16* __restrict__ w0g,
    const u16* __restrict__ w1g, const u16* __restrict__ w2g, const u16* __restrict__ w3g,
    const float* __restrict__ b_in, const float* __restrict__ b_h0, const float* __restrict__ b_h1,
    float* __restrict__ logits, float* __restrict__ outputs)
{
    __shared__ u16 hA[128 * 128];   // h0 (128x128), later reused for h2 (128x64)
    __shared__ u16 hB[128 * 128];   // h1 (128x128)

    const int f  = blockIdx.x >> 6;
    const int bt = blockIdx.x & (NBT - 1);
    const int t  = threadIdx.x;
    const int w  = t >> 6;
    const int lane = t & 63;
    const int lo = lane & 15;
    const int hi = lane >> 4;

    // ---------------- layer 0: h0[b][o] = relu(x[b]*w0[o] + b_in[o]) --------
    {
        const int og = t & 15;       // cols og*8 .. og*8+7
        const int bg = t >> 4;       // rows bg*8 .. bg*8+7
        bf16x8 w0v = *(const bf16x8*)(w0g + f * 128 + og * 8);
        f32x4 bi0 = *(const f32x4*)(b_in + f * 128 + og * 8);
        f32x4 bi1 = *(const f32x4*)(b_in + f * 128 + og * 8 + 4);
        bf16x8 xv = *(const bf16x8*)(x_t + (size_t)f * NBATCH + bt * BT + bg * 8);
        float wf[8], bb_[8];
        #pragma unroll
        for (int j = 0; j < 8; j++) wf[j] = bf2f((u16)w0v[j]);
        bb_[0] = bi0[0]; bb_[1] = bi0[1]; bb_[2] = bi0[2]; bb_[3] = bi0[3];
        bb_[4] = bi1[0]; bb_[5] = bi1[1]; bb_[6] = bi1[2]; bb_[7] = bi1[3];
        #pragma unroll
        for (int r = 0; r < 8; r++) {
            const int b = bg * 8 + r;
            const float x = bf2f((u16)xv[r]);
            u32 pk[4];
            #pragma unroll
            for (int j = 0; j < 4; j++) {
                u16 e0 = f2bf(fmaxf(0.f, fmaf(x, wf[2 * j],     bb_[2 * j])));
                u16 e1 = f2bf(fmaxf(0.f, fmaf(x, wf[2 * j + 1], bb_[2 * j + 1])));
                pk[j] = (u32)e0 | ((u32)e1 << 16);
            }
            char* dst = (char*)hA + (((b * 128 + og * 8) * 2) ^ ((b & 7) << 4));
            *(uint4*)dst = make_uint4(pk[0], pk[1], pk[2], pk[3]);
        }
    }
    __syncthreads();

    // ---------------- layer 1: h1 = relu(W1 (128x128) . h0^T + b_h0) --------
    {
        const int wo = w >> 1, wb = w & 1;
        f32x4 acc[4][4] = {};
        const u16* wbase = w1g + ((size_t)(f * 128 + wo * 64 + lo)) * 128 + hi * 8;
        #pragma unroll
        for (int ks = 0; ks < 4; ks++) {
            bf16x8 a[4], bm[4];
            #pragma unroll
            for (int m = 0; m < 4; m++)
                a[m] = *(const bf16x8*)(wbase + m * 16 * 128 + ks * 32);
            #pragma unroll
            for (int n = 0; n < 4; n++) {
                const int b = wb * 64 + n * 16 + lo;
                const char* p = (const char*)hA + (((b * 128 + ks * 32 + hi * 8) * 2) ^ ((b & 7) << 4));
                bm[n] = *(const bf16x8*)p;
            }
            #pragma unroll
            for (int m = 0; m < 4; m++)
                #pragma unroll
                for (int n = 0; n < 4; n++)
                    acc[m][n] = mfma16(a[m], bm[n], acc[m][n]);
        }
        #pragma unroll
        for (int m = 0; m < 4; m++) {
            const int ob = wo * 64 + m * 16 + hi * 4;
            f32x4 bs = *(const f32x4*)(b_h0 + f * 128 + ob);
            #pragma unroll
            for (int n = 0; n < 4; n++) {
                const int b = wb * 64 + n * 16 + lo;
                u16 q0 = f2bf(fmaxf(0.f, acc[m][n][0] + bs[0]));
                u16 q1 = f2bf(fmaxf(0.f, acc[m][n][1] + bs[1]));
                u16 q2 = f2bf(fmaxf(0.f, acc[m][n][2] + bs[2]));
                u16 q3 = f2bf(fmaxf(0.f, acc[m][n][3] + bs[3]));
                char* dst = (char*)hB + (((b * 128 + ob) * 2) ^ ((b & 7) << 4));
                *(uint2*)dst = make_uint2((u32)q0 | ((u32)q1 << 16), (u32)q2 | ((u32)q3 << 16));
            }
        }
    }
    __syncthreads();

    // ---------------- layer 2: h2 = relu(W2 (64x128) . h1^T + b_h1) ---------
    // h2 stored into hA as [b][64]
    {
        const int wo = w >> 1, wb = w & 1;
        f32x4 acc[2][4] = {};
        const u16* wbase = w2g + ((size_t)(f * 64 + wo * 32 + lo)) * 128 + hi * 8;
        #pragma unroll
        for (int ks = 0; ks < 4; ks++) {
            bf16x8 a[2], bm[4];
            #pragma unroll
            for (int m = 0; m < 2; m++)
                a[m] = *(const bf16x8*)(wbase + m * 16 * 128 + ks * 32);
            #pragma unroll
            for (int n = 0; n < 4; n++) {
                const int b = wb * 64 + n * 16 + lo;
                const char* p = (const char*)hB + (((b * 128 + ks * 32 + hi * 8) * 2) ^ ((b & 7) << 4));
                bm[n] = *(const bf16x8*)p;
            }
            #pragma unroll
            for (int m = 0; m < 2; m++)
                #pragma unroll
                for (int n = 0; n < 4; n++)
                    acc[m][n] = mfma16(a[m], bm[n], acc[m][n]);
        }
        #pragma unroll
        for (int m = 0; m < 2; m++) {
            const int ob = wo * 32 + m * 16 + hi * 4;
            f32x4 bs = *(const f32x4*)(b_h1 + f * 64 + ob);
            #pragma unroll
            for (int n = 0; n < 4; n++) {
                const int b = wb * 64 + n * 16 + lo;
                u16 q0 = f2bf(fmaxf(0.f, acc[m][n][0] + bs[0]));
                u16 q1 = f2bf(fmaxf(0.f, acc[m][n][1] + bs[1]));
                u16 q2 = f2bf(fmaxf(0.f, acc[m][n][2] + bs[2]));
                u16 q3 = f2bf(fmaxf(0.f, acc[m][n][3] + bs[3]));
                char* dst = (char*)hA + (((b * 64 + ob) * 2) ^ ((b & 7) << 4));
                *(uint2*)dst = make_uint2((u32)q0 | ((u32)q1 << 16), (u32)q2 | ((u32)q3 << 16));
            }
        }
    }
    __syncthreads();

    // ---------------- layer 3: out = W3 (16x64) . h2^T ----------------------
    {
        f32x4 acc[2] = {};
        const u16* wbase = w3g + ((size_t)(f * 16 + lo)) * 64 + hi * 8;
        #pragma unroll
        for (int ks = 0; ks < 2; ks++) {
            bf16x8 a = *(const bf16x8*)(wbase + ks * 32);
            #pragma unroll
            for (int n = 0; n < 2; n++) {
                const int b = w * 32 + n * 16 + lo;
                const char* p = (const char*)hA + (((b * 64 + ks * 32 + hi * 8) * 2) ^ ((b & 7) << 4));
                bf16x8 bm = *(const bf16x8*)p;
                acc[n] = mfma16(a, bm, acc[n]);
            }
        }
        #pragma unroll
        for (int n = 0; n < 2; n++) {
            const int gb = bt * BT + w * 32 + n * 16 + lo;  // global batch row
            float* op = outputs + ((size_t)gb * NFEAT + f) * 16 + hi * 4;
            *(f32x4*)op = acc[n];
            #pragma unroll
            for (int r = 0; r < 4; r++)
                atomicAdd(logits + gb * 16 + hi * 4 + r, acc[n][r]);
        }
    }
}

// ---------------------------------------------------------------------------
extern "C" void kernel_launch(void* const* d_in, const int* in_sizes, int n_in,
                              void* d_out, int out_size, void* d_ws, size_t ws_size,
                              hipStream_t stream) {
    const float* tab   = (const float*)d_in[0];
    const float* v_in  = (const float*)d_in[1];
    const float* g_in  = (const float*)d_in[2];
    const float* b_in  = (const float*)d_in[3];
    const float* v_h0  = (const float*)d_in[4];
    const float* g_h0  = (const float*)d_in[5];
    const float* b_h0  = (const float*)d_in[6];
    const float* v_h1  = (const float*)d_in[7];
    const float* g_h1  = (const float*)d_in[8];
    const float* b_h1  = (const float*)d_in[9];
    const float* v_out = (const float*)d_in[10];
    const float* g_out = (const float*)d_in[11];
    const float* bias  = (const float*)d_in[12];

    char* ws = (char*)d_ws;
    u16* w0  = (u16*)(ws);                         //  32768 * 2
    u16* w1  = (u16*)(ws + 65536);                 // 4194304 * 2
    u16* w2  = (u16*)(ws + 65536 + 8388608);       // 2097152 * 2
    u16* w3  = (u16*)(ws + 12648448);              //  262144 * 2
    u16* x_t = (u16*)(ws + 13172736);              // 2097152 * 2  (end ~17.4MB)

    float* logits  = (float*)d_out;
    float* outputs = (float*)d_out + (size_t)NBATCH * 16;

    hipLaunchKernelGGL(prep_w0,     dim3(128),   dim3(256), 0, stream, v_in, g_in, w0);
    hipLaunchKernelGGL(prep_norm,   dim3(13312), dim3(256), 0, stream,
                       v_h0, g_h0, v_h1, g_h1, v_out, g_out, w1, w2, w3);
    hipLaunchKernelGGL(prep_x,      dim3(512),   dim3(256), 0, stream, tab, x_t);
    hipLaunchKernelGGL(init_logits, dim3(512),   dim3(256), 0, stream, logits, bias);
    hipLaunchKernelGGL(nam_main,    dim3(NFEAT * NBT), dim3(256), 0, stream,
                       x_t, w0, w1, w2, w3, b_in, b_h0, b_h1, logits, outputs);
}

// Round 2
// 294.077 us; speedup vs baseline: 1.5468x; 1.5468x over previous
//
#include <hip/hip_runtime.h>

typedef unsigned short u16;
typedef unsigned int   u32;
typedef __attribute__((ext_vector_type(8))) short bf16x8;
typedef __attribute__((ext_vector_type(4))) float f32x4;
typedef __attribute__((ext_vector_type(2))) float f32x2;

#define NFEAT  256
#define NBATCH 8192
#define BT     128   // batch tile per block
#define NBT    (NBATCH / BT)   // 64

__device__ __forceinline__ u16 f2bf(float f) {
    u32 u = __builtin_bit_cast(u32, f);
    return (u16)((u + 0x7FFFu + ((u >> 16) & 1u)) >> 16);
}
__device__ __forceinline__ float bf2f(u16 h) {
    return __builtin_bit_cast(float, (u32)h << 16);
}
__device__ __forceinline__ u32 cvtpk(float a, float b) {
    u32 r;
    asm("v_cvt_pk_bf16_f32 %0, %1, %2" : "=v"(r) : "v"(a), "v"(b));
    return r;   // lo16 = bf16(a), hi16 = bf16(b), RNE
}
__device__ __forceinline__ f32x4 mfma16(bf16x8 a, bf16x8 b, f32x4 c) {
    return __builtin_amdgcn_mfma_f32_16x16x32_bf16(a, b, c, 0, 0, 0);
}

// ---------------------------------------------------------------------------
// prep: w0[f,o] = g_in[f,o] * sign(v_in[f,o,0])   (norm over a length-1 axis)
// ---------------------------------------------------------------------------
__global__ void prep_w0(const float* __restrict__ v_in, const float* __restrict__ g_in,
                        u16* __restrict__ w0) {
    int i = blockIdx.x * blockDim.x + threadIdx.x;   // < 32768
    float v = v_in[i];
    float g = g_in[i];
    w0[i] = f2bf(v >= 0.f ? g : -g);
}

// ---------------------------------------------------------------------------
// prep: weight-normalize v_h0/v_h1/v_out rows -> bf16.  One wave per row.
// ---------------------------------------------------------------------------
__global__ void prep_norm(const float* __restrict__ v_h0, const float* __restrict__ g_h0,
                          const float* __restrict__ v_h1, const float* __restrict__ g_h1,
                          const float* __restrict__ v_out, const float* __restrict__ g_out,
                          u16* __restrict__ w1, u16* __restrict__ w2, u16* __restrict__ w3) {
    const int wave = (blockIdx.x * blockDim.x + threadIdx.x) >> 6;
    const int lane = threadIdx.x & 63;
    if (wave < 32768 + 16384) {
        const float* src; u16* dst; float g;
        if (wave < 32768) {
            src = v_h0 + (size_t)wave * 128; dst = w1 + (size_t)wave * 128; g = g_h0[wave];
        } else {
            int r = wave - 32768;
            src = v_h1 + (size_t)r * 128; dst = w2 + (size_t)r * 128; g = g_h1[r];
        }
        f32x2 v = *(const f32x2*)(src + lane * 2);
        float ss = v.x * v.x + v.y * v.y;
        #pragma unroll
        for (int off = 32; off; off >>= 1) ss += __shfl_xor(ss, off);
        float s = g * rsqrtf(ss);
        *(u32*)(dst + lane * 2) = cvtpk(v.x * s, v.y * s);
    } else {
        int r = wave - 49152;   // < 4096
        const float* src = v_out + (size_t)r * 64;
        float v = src[lane];
        float ss = v * v;
        #pragma unroll
        for (int off = 32; off; off >>= 1) ss += __shfl_xor(ss, off);
        float s = g_out[r] * rsqrtf(ss);
        w3[(size_t)r * 64 + lane] = f2bf(v * s);
    }
}

// ---------------------------------------------------------------------------
// prep: x_t[f][b] = bf16( tab[b,0,f] * (1 - tab[b,1,f]) )   (64x64 LDS transpose)
// ---------------------------------------------------------------------------
__global__ void prep_x(const float* __restrict__ tab, u16* __restrict__ x_t) {
    __shared__ u16 tile[64][65];
    const int bb = (blockIdx.x % (NBATCH / 64)) * 64;
    const int ff = (blockIdx.x / (NBATCH / 64)) * 64;
    const int tr = threadIdx.x >> 6;    // 0..3
    const int tc = threadIdx.x & 63;
    #pragma unroll
    for (int i = 0; i < 16; i++) {
        int b = bb + tr + i * 4;
        float val  = tab[(size_t)b * 512 + ff + tc];
        float miss = tab[(size_t)b * 512 + 256 + ff + tc];
        tile[tr + i * 4][tc] = f2bf(val * (1.f - miss));
    }
    __syncthreads();
    #pragma unroll
    for (int i = 0; i < 16; i++) {
        int fr = tr + i * 4;
        x_t[(size_t)(ff + fr) * NBATCH + bb + tc] = tile[tc][fr];
    }
}

// ---------------------------------------------------------------------------
// logits[b][j] = bias[j] + sum_f outputs[b][f][j]
// block = 4 waves, one b per wave; lane = fo*4 + j4 -> fully coalesced 1KB/instr
// ---------------------------------------------------------------------------
__global__ void reduce_logits(const float* __restrict__ outputs,
                              const float* __restrict__ bias,
                              float* __restrict__ logits) {
    const int b = blockIdx.x * 4 + (threadIdx.x >> 6);
    const int lane = threadIdx.x & 63;
    const int j4 = lane & 3;     // output quad
    const int fo = lane >> 2;    // feature offset 0..15
    const float* base = outputs + (size_t)b * (NFEAT * 16);
    f32x4 acc = {};
    #pragma unroll
    for (int it = 0; it < 16; it++) {
        f32x4 v = *(const f32x4*)(base + (fo + it * 16) * 16 + j4 * 4);
        acc[0] += v[0]; acc[1] += v[1]; acc[2] += v[2]; acc[3] += v[3];
    }
    #pragma unroll
    for (int off = 4; off < 64; off <<= 1) {
        acc[0] += __shfl_xor(acc[0], off);
        acc[1] += __shfl_xor(acc[1], off);
        acc[2] += __shfl_xor(acc[2], off);
        acc[3] += __shfl_xor(acc[3], off);
    }
    if (lane < 4) {
        f32x4 bs = *(const f32x4*)(bias + lane * 4);
        acc[0] += bs[0]; acc[1] += bs[1]; acc[2] += bs[2]; acc[3] += bs[3];
        *(f32x4*)(logits + b * 16 + lane * 4) = acc;
    }
}

// ---------------------------------------------------------------------------
// main: per (feature f, batch-tile bt) block, chain 4 layers via MFMA.
// XCD swizzle: f = (bid%8)*32 + (bid/8)%32, bt = bid/256  -> all 64 bt-blocks
// of one f run on ONE XCD concurrently; 32 live f x 68KB = 2.2MB fits L2.
// ---------------------------------------------------------------------------
__global__ __launch_bounds__(256, 2) void nam_main(
    const u16* __restrict__ x_t, const u16* __restrict__ w0g,
    const u16* __restrict__ w1g, const u16* __restrict__ w2g, const u16* __restrict__ w3g,
    const float* __restrict__ b_in, const float* __restrict__ b_h0, const float* __restrict__ b_h1,
    float* __restrict__ outputs)
{
    __shared__ u16 hA[128 * 128];   // h0 (128x128), later reused for h2 (128x64)
    __shared__ u16 hB[128 * 128];   // h1 (128x128)

    const int bid = blockIdx.x;
    const int f  = (bid & 7) * 32 + ((bid >> 3) & 31);
    const int bt = bid >> 8;
    const int t  = threadIdx.x;
    const int w  = t >> 6;
    const int lane = t & 63;
    const int lo = lane & 15;
    const int hi = lane >> 4;

    // ---------------- layer 0: h0[b][o] = relu(x[b]*w0[o] + b_in[o]) --------
    {
        const int og = t & 15;       // cols og*8 .. og*8+7
        const int bg = t >> 4;       // rows bg*8 .. bg*8+7
        bf16x8 w0v = *(const bf16x8*)(w0g + f * 128 + og * 8);
        f32x4 bi0 = *(const f32x4*)(b_in + f * 128 + og * 8);
        f32x4 bi1 = *(const f32x4*)(b_in + f * 128 + og * 8 + 4);
        bf16x8 xv = *(const bf16x8*)(x_t + (size_t)f * NBATCH + bt * BT + bg * 8);
        float wf[8], bb_[8];
        #pragma unroll
        for (int j = 0; j < 8; j++) wf[j] = bf2f((u16)w0v[j]);
        bb_[0] = bi0[0]; bb_[1] = bi0[1]; bb_[2] = bi0[2]; bb_[3] = bi0[3];
        bb_[4] = bi1[0]; bb_[5] = bi1[1]; bb_[6] = bi1[2]; bb_[7] = bi1[3];
        #pragma unroll
        for (int r = 0; r < 8; r++) {
            const int b = bg * 8 + r;
            const float x = bf2f((u16)xv[r]);
            u32 pk[4];
            #pragma unroll
            for (int j = 0; j < 4; j++) {
                float e0 = fmaxf(0.f, fmaf(x, wf[2 * j],     bb_[2 * j]));
                float e1 = fmaxf(0.f, fmaf(x, wf[2 * j + 1], bb_[2 * j + 1]));
                pk[j] = cvtpk(e0, e1);
            }
            char* dst = (char*)hA + (((b * 128 + og * 8) * 2) ^ ((b & 7) << 4));
            *(uint4*)dst = make_uint4(pk[0], pk[1], pk[2], pk[3]);
        }
    }
    __syncthreads();

    // ---------------- layer 1: h1 = relu(W1 (128x128) . h0^T + b_h0) --------
    {
        const int wo = w >> 1, wb = w & 1;
        f32x4 acc[4][4] = {};
        const u16* wbase = w1g + ((size_t)(f * 128 + wo * 64 + lo)) * 128 + hi * 8;
        #pragma unroll
        for (int ks = 0; ks < 4; ks++) {
            bf16x8 a[4], bm[4];
            #pragma unroll
            for (int m = 0; m < 4; m++)
                a[m] = *(const bf16x8*)(wbase + m * 16 * 128 + ks * 32);
            #pragma unroll
            for (int n = 0; n < 4; n++) {
                const int b = wb * 64 + n * 16 + lo;
                const char* p = (const char*)hA + (((b * 128 + ks * 32 + hi * 8) * 2) ^ ((b & 7) << 4));
                bm[n] = *(const bf16x8*)p;
            }
            #pragma unroll
            for (int m = 0; m < 4; m++)
                #pragma unroll
                for (int n = 0; n < 4; n++)
                    acc[m][n] = mfma16(a[m], bm[n], acc[m][n]);
        }
        #pragma unroll
        for (int m = 0; m < 4; m++) {
            const int ob = wo * 64 + m * 16 + hi * 4;
            f32x4 bs = *(const f32x4*)(b_h0 + f * 128 + ob);
            #pragma unroll
            for (int n = 0; n < 4; n++) {
                const int b = wb * 64 + n * 16 + lo;
                float r0 = fmaxf(0.f, acc[m][n][0] + bs[0]);
                float r1 = fmaxf(0.f, acc[m][n][1] + bs[1]);
                float r2 = fmaxf(0.f, acc[m][n][2] + bs[2]);
                float r3 = fmaxf(0.f, acc[m][n][3] + bs[3]);
                char* dst = (char*)hB + (((b * 128 + ob) * 2) ^ ((b & 7) << 4));
                *(uint2*)dst = make_uint2(cvtpk(r0, r1), cvtpk(r2, r3));
            }
        }
    }
    __syncthreads();

    // ---------------- layer 2: h2 = relu(W2 (64x128) . h1^T + b_h1) ---------
    {
        const int wo = w >> 1, wb = w & 1;
        f32x4 acc[2][4] = {};
        const u16* wbase = w2g + ((size_t)(f * 64 + wo * 32 + lo)) * 128 + hi * 8;
        #pragma unroll
        for (int ks = 0; ks < 4; ks++) {
            bf16x8 a[2], bm[4];
            #pragma unroll
            for (int m = 0; m < 2; m++)
                a[m] = *(const bf16x8*)(wbase + m * 16 * 128 + ks * 32);
            #pragma unroll
            for (int n = 0; n < 4; n++) {
                const int b = wb * 64 + n * 16 + lo;
                const char* p = (const char*)hB + (((b * 128 + ks * 32 + hi * 8) * 2) ^ ((b & 7) << 4));
                bm[n] = *(const bf16x8*)p;
            }
            #pragma unroll
            for (int m = 0; m < 2; m++)
                #pragma unroll
                for (int n = 0; n < 4; n++)
                    acc[m][n] = mfma16(a[m], bm[n], acc[m][n]);
        }
        #pragma unroll
        for (int m = 0; m < 2; m++) {
            const int ob = wo * 32 + m * 16 + hi * 4;
            f32x4 bs = *(const f32x4*)(b_h1 + f * 64 + ob);
            #pragma unroll
            for (int n = 0; n < 4; n++) {
                const int b = wb * 64 + n * 16 + lo;
                float r0 = fmaxf(0.f, acc[m][n][0] + bs[0]);
                float r1 = fmaxf(0.f, acc[m][n][1] + bs[1]);
                float r2 = fmaxf(0.f, acc[m][n][2] + bs[2]);
                float r3 = fmaxf(0.f, acc[m][n][3] + bs[3]);
                char* dst = (char*)hA + (((b * 64 + ob) * 2) ^ ((b & 7) << 4));
                *(uint2*)dst = make_uint2(cvtpk(r0, r1), cvtpk(r2, r3));
            }
        }
    }
    __syncthreads();

    // ---------------- layer 3: out = W3 (16x64) . h2^T ----------------------
    {
        f32x4 acc[2] = {};
        const u16* wbase = w3g + ((size_t)(f * 16 + lo)) * 64 + hi * 8;
        #pragma unroll
        for (int ks = 0; ks < 2; ks++) {
            bf16x8 a = *(const bf16x8*)(wbase + ks * 32);
            #pragma unroll
            for (int n = 0; n < 2; n++) {
                const int b = w * 32 + n * 16 + lo;
                const char* p = (const char*)hA + (((b * 64 + ks * 32 + hi * 8) * 2) ^ ((b & 7) << 4));
                bf16x8 bm = *(const bf16x8*)p;
                acc[n] = mfma16(a, bm, acc[n]);
            }
        }
        #pragma unroll
        for (int n = 0; n < 2; n++) {
            const int gb = bt * BT + w * 32 + n * 16 + lo;  // global batch row
            float* op = outputs + ((size_t)gb * NFEAT + f) * 16 + hi * 4;
            *(f32x4*)op = acc[n];
        }
    }
}

// ---------------------------------------------------------------------------
extern "C" void kernel_launch(void* const* d_in, const int* in_sizes, int n_in,
                              void* d_out, int out_size, void* d_ws, size_t ws_size,
                              hipStream_t stream) {
    const float* tab   = (const float*)d_in[0];
    const float* v_in  = (const float*)d_in[1];
    const float* g_in  = (const float*)d_in[2];
    const float* b_in  = (const float*)d_in[3];
    const float* v_h0  = (const float*)d_in[4];
    const float* g_h0  = (const float*)d_in[5];
    const float* b_h0  = (const float*)d_in[6];
    const float* v_h1  = (const float*)d_in[7];
    const float* g_h1  = (const float*)d_in[8];
    const float* b_h1  = (const float*)d_in[9];
    const float* v_out = (const float*)d_in[10];
    const float* g_out = (const float*)d_in[11];
    const float* bias  = (const float*)d_in[12];

    char* ws = (char*)d_ws;
    u16* w0  = (u16*)(ws);                         //  32768 * 2
    u16* w1  = (u16*)(ws + 65536);                 // 4194304 * 2
    u16* w2  = (u16*)(ws + 65536 + 8388608);       // 2097152 * 2
    u16* w3  = (u16*)(ws + 12648448);              //  262144 * 2
    u16* x_t = (u16*)(ws + 13172736);              // 2097152 * 2  (end ~17.4MB)

    float* logits  = (float*)d_out;
    float* outputs = (float*)d_out + (size_t)NBATCH * 16;

    hipLaunchKernelGGL(prep_w0,   dim3(128),   dim3(256), 0, stream, v_in, g_in, w0);
    hipLaunchKernelGGL(prep_norm, dim3(13312), dim3(256), 0, stream,
                       v_h0, g_h0, v_h1, g_h1, v_out, g_out, w1, w2, w3);
    hipLaunchKernelGGL(prep_x,    dim3(512),   dim3(256), 0, stream, tab, x_t);
    hipLaunchKernelGGL(nam_main,  dim3(NFEAT * NBT), dim3(256), 0, stream,
                       x_t, w0, w1, w2, w3, b_in, b_h0, b_h1, outputs);
    hipLaunchKernelGGL(reduce_logits, dim3(NBATCH / 4), dim3(256), 0, stream,
                       outputs, bias, logits);
}